// Round 1
// baseline (1284.347 us; speedup 1.0000x reference)
//
#include <hip/hip_runtime.h>
#include <hip/hip_bf16.h>

#define NA 100000
#define NE 800000
#define FDIM 133
#define KIN 192          // 133 padded to 3*64
#define H 256
#define NMOL 4096

typedef __attribute__((ext_vector_type(8))) short s16x8;
typedef __attribute__((ext_vector_type(4))) float f32x4;
typedef __attribute__((ext_vector_type(4))) unsigned short u16x4;

__device__ __forceinline__ float bf2f(unsigned short h) {
    unsigned u = ((unsigned)h) << 16;
    return __builtin_bit_cast(float, u);
}
__device__ __forceinline__ unsigned short f2bf(float f) {
    unsigned u = __builtin_bit_cast(unsigned, f);
    u = u + 0x7FFFu + ((u >> 16) & 1u);
    return (unsigned short)(u >> 16);
}

// element offset (in shorts) of 16B group g (0..7) of row (0..127) in a [128][64] bf16 tile,
// XOR-swizzled so both ds_write_b128 staging and MFMA-frag ds_read_b128 are conflict-optimal
__device__ __forceinline__ int swz(int row, int g) {
    return row * 64 + ((g ^ (row & 7)) << 3);
}

// ---------------- GEMM: C[M][256] = A[M][Kpad] * BT[256][Kpad]^T (+bias) ----------------
// AFFINE: A' = relu(A*aSc[k]+aSh[k]) applied during staging (folds previous BN+ReLU)
// RELU_OUT: relu on output (input layer)
template<bool AFFINE, bool RELU_OUT>
__global__ __launch_bounds__(256) void gemm_k(
    const unsigned short* __restrict__ A,
    const unsigned short* __restrict__ BT,
    const float* __restrict__ bias,
    const float* __restrict__ aSc, const float* __restrict__ aSh,
    unsigned short* __restrict__ C,
    int M, int Kpad)
{
    __shared__ short lsA[128 * 64];
    __shared__ short lsB[128 * 64];
    __shared__ float lsSc[256], lsSh[256];

    const int t = threadIdx.x;
    const int m0 = blockIdx.y * 128;
    const int n0 = blockIdx.x * 128;

    if (AFFINE) { lsSc[t] = aSc[t]; lsSh[t] = aSh[t]; }
    if (AFFINE) __syncthreads();

    const int sr = t >> 3;          // staging row-in-pass 0..31
    const int sg = t & 7;           // staging 16B group 0..7
    const int lane = t & 63;
    const int wid = t >> 6;
    const int wm = wid >> 1, wn = wid & 1;
    const int fr = lane & 15, fg = lane >> 4;

    f32x4 acc[4][4];
    #pragma unroll
    for (int i = 0; i < 4; i++)
        #pragma unroll
        for (int j = 0; j < 4; j++)
            acc[i][j] = f32x4{0.f, 0.f, 0.f, 0.f};

    const int nK = Kpad >> 6;
    s16x8 ra[4], rb[4];

    auto loadRegs = [&](int kc) {
        const int k0 = kc * 64;
        #pragma unroll
        for (int p = 0; p < 4; ++p) {
            int r = p * 32 + sr;
            int ga = m0 + r;
            s16x8 z = {0,0,0,0,0,0,0,0};
            ra[p] = (ga < M) ? *(const s16x8*)(A + (size_t)ga * Kpad + k0 + sg * 8) : z;
            rb[p] = *(const s16x8*)(BT + (size_t)(n0 + r) * Kpad + k0 + sg * 8);
        }
    };
    auto writeLds = [&](int kc) {
        const int k0 = kc * 64;
        #pragma unroll
        for (int p = 0; p < 4; ++p) {
            int r = p * 32 + sr;
            s16x8 va = ra[p];
            if (AFFINE) {
                #pragma unroll
                for (int e = 0; e < 8; ++e) {
                    int k = k0 + sg * 8 + e;
                    float f = bf2f((unsigned short)va[e]);
                    f = fmaxf(f * lsSc[k] + lsSh[k], 0.f);
                    va[e] = (short)f2bf(f);
                }
            }
            *(s16x8*)&lsA[swz(r, sg)] = va;
            *(s16x8*)&lsB[swz(r, sg)] = rb[p];
        }
    };

    loadRegs(0);
    for (int kc = 0; kc < nK; ++kc) {
        writeLds(kc);
        __syncthreads();
        if (kc + 1 < nK) loadRegs(kc + 1);   // issue next-chunk loads, overlap with MFMA
        #pragma unroll
        for (int ks = 0; ks < 2; ++ks) {
            s16x8 af[4], bg[4];
            #pragma unroll
            for (int mi = 0; mi < 4; ++mi)
                af[mi] = *(const s16x8*)&lsA[swz(wm * 64 + mi * 16 + fr, ks * 4 + fg)];
            #pragma unroll
            for (int ni = 0; ni < 4; ++ni)
                bg[ni] = *(const s16x8*)&lsB[swz(wn * 64 + ni * 16 + fr, ks * 4 + fg)];
            #pragma unroll
            for (int mi = 0; mi < 4; ++mi)
                #pragma unroll
                for (int ni = 0; ni < 4; ++ni)
                    acc[mi][ni] = __builtin_amdgcn_mfma_f32_16x16x32_bf16(
                        af[mi], bg[ni], acc[mi][ni], 0, 0, 0);
        }
        __syncthreads();
    }

    // epilogue: C/D layout col = lane&15, row = (lane>>4)*4 + reg
    float bc[4];
    #pragma unroll
    for (int ni = 0; ni < 4; ++ni)
        bc[ni] = bias[n0 + wn * 64 + ni * 16 + fr];
    #pragma unroll
    for (int mi = 0; mi < 4; ++mi) {
        #pragma unroll
        for (int r = 0; r < 4; ++r) {
            int row = m0 + wm * 64 + mi * 16 + fg * 4 + r;
            if (row < M) {
                #pragma unroll
                for (int ni = 0; ni < 4; ++ni) {
                    float v = acc[mi][ni][r] + bc[ni];
                    if (RELU_OUT) v = fmaxf(v, 0.f);
                    C[(size_t)row * H + n0 + wn * 64 + ni * 16 + fr] = f2bf(v);
                }
            }
        }
    }
}

// ---------------- column stats (sum, sumsq) of bf16 [NA][256] ----------------
__global__ __launch_bounds__(256) void stats_k(const unsigned short* __restrict__ T,
                                               float* __restrict__ sum, float* __restrict__ sumsq) {
    int c = threadIdx.x;
    int r0 = blockIdx.x * 391;
    int r1 = r0 + 391; if (r1 > NA) r1 = NA;
    float s = 0.f, q = 0.f;
    for (int r = r0; r < r1; ++r) {
        float v = bf2f(T[(size_t)r * H + c]);
        s += v; q += v * v;
    }
    atomicAdd(&sum[c], s);
    atomicAdd(&sumsq[c], q);
}

__global__ void bnfin_k(float* __restrict__ sum, float* __restrict__ sumsq,
                        const float* __restrict__ g, const float* __restrict__ be,
                        float* __restrict__ scOut, float* __restrict__ shOut) {
    int c = threadIdx.x;
    float mean = sum[c] * (1.0f / NA);
    float var = sumsq[c] * (1.0f / NA) - mean * mean;
    float sc = g[c] * rsqrtf(var + 1e-5f);
    scOut[c] = sc;
    shOut[c] = be[c] - mean * sc;
    sum[c] = 0.f; sumsq[c] = 0.f;   // ready for next use
}

// ---------------- CSR build ----------------
__global__ void zero_i32_k(int* p, int n) { int i = blockIdx.x * 256 + threadIdx.x; if (i < n) p[i] = 0; }
__global__ void zero_f32_k(float* p, int n) { int i = blockIdx.x * 256 + threadIdx.x; if (i < n) p[i] = 0.f; }

__global__ void hist_k(const int* __restrict__ dst, int* __restrict__ counts) {
    int e = blockIdx.x * 256 + threadIdx.x;
    if (e < NE) atomicAdd(&counts[dst[e]], 1);
}
__global__ void scan1_k(const int* __restrict__ counts, int* __restrict__ excl, int* __restrict__ bsum) {
    __shared__ int sd[256];
    int i = blockIdx.x * 256 + threadIdx.x;
    int c = (i < NA) ? counts[i] : 0;
    sd[threadIdx.x] = c;
    __syncthreads();
    for (int off = 1; off < 256; off <<= 1) {
        int v = (threadIdx.x >= off) ? sd[threadIdx.x - off] : 0;
        __syncthreads();
        sd[threadIdx.x] += v;
        __syncthreads();
    }
    if (i < NA) excl[i] = sd[threadIdx.x] - c;
    if (threadIdx.x == 255) bsum[blockIdx.x] = sd[255];
}
__global__ void scan2_k(int* __restrict__ bsum, int nb) {
    __shared__ int sd[512];
    int t = threadIdx.x;
    int v = (t < nb) ? bsum[t] : 0;
    sd[t] = v;
    __syncthreads();
    for (int off = 1; off < 512; off <<= 1) {
        int u = (t >= off) ? sd[t - off] : 0;
        __syncthreads();
        sd[t] += u;
        __syncthreads();
    }
    if (t < nb) bsum[t] = sd[t] - v;
}
__global__ void scan3_k(int* __restrict__ rowstart, const int* __restrict__ bsum, int* __restrict__ cursor) {
    int i = blockIdx.x * 256 + threadIdx.x;
    if (i < NA) {
        int v = rowstart[i] + bsum[blockIdx.x];
        rowstart[i] = v;
        cursor[i] = v;
    }
}
__global__ void fill_k(const int* __restrict__ src, const int* __restrict__ dstArr,
                       int* __restrict__ cursor, int* __restrict__ esrc) {
    int e = blockIdx.x * 256 + threadIdx.x;
    if (e < NE) {
        int d = dstArr[e];
        int pos = atomicAdd(&cursor[d], 1);
        esrc[pos] = src[e];
    }
}

// ---------------- neighbor aggregation: AGG[r] = (1+eps)*x'[r] + sum_{s in N(r)} x'[s] ----------------
// AFF: x' = relu(X*sc+sh) (folds previous layer's BN+ReLU); else x' = X
template<bool AFF>
__global__ __launch_bounds__(256) void agg_k(const unsigned short* __restrict__ X,
    const float* __restrict__ sc, const float* __restrict__ sh,
    const int* __restrict__ rowstart, const int* __restrict__ counts,
    const int* __restrict__ esrc, const float* __restrict__ epsArr, int layer,
    unsigned short* __restrict__ AGG)
{
    int wid = threadIdx.x >> 6, lane = threadIdx.x & 63;
    int row = blockIdx.x * 4 + wid;
    if (row >= NA) return;
    int c0 = lane * 4;
    float e1 = 1.0f + epsArr[layer];
    f32x4 s4{0,0,0,0}, h4{0,0,0,0};
    if (AFF) { s4 = *(const f32x4*)(sc + c0); h4 = *(const f32x4*)(sh + c0); }

    f32x4 acc;
    {
        u16x4 u = *(const u16x4*)(X + (size_t)row * H + c0);
        #pragma unroll
        for (int e = 0; e < 4; e++) {
            float f = bf2f(u[e]);
            if (AFF) f = fmaxf(f * s4[e] + h4[e], 0.f);
            acc[e] = f * e1;
        }
    }
    int s = rowstart[row], eEnd = s + counts[row];
    for (int i = s; i < eEnd; ++i) {
        int sr2 = esrc[i];
        u16x4 u = *(const u16x4*)(X + (size_t)sr2 * H + c0);
        #pragma unroll
        for (int e = 0; e < 4; e++) {
            float f = bf2f(u[e]);
            if (AFF) f = fmaxf(f * s4[e] + h4[e], 0.f);
            acc[e] += f;
        }
    }
    u16x4 o;
    #pragma unroll
    for (int e = 0; e < 4; e++) o[e] = f2bf(acc[e]);
    *(u16x4*)(AGG + (size_t)row * H + c0) = o;
}

// ---------------- input feature cast + pad ----------------
__global__ void cast_fa_k(const float* __restrict__ fa, unsigned short* __restrict__ FA) {
    long long i = (long long)blockIdx.x * 256 + threadIdx.x;
    if (i < (long long)NA * KIN) {
        int r = (int)(i / KIN), k = (int)(i % KIN);
        FA[i] = (k < FDIM) ? f2bf(fa[(size_t)r * FDIM + k]) : (unsigned short)0;
    }
}
// W [K][256] fp32 -> BT [256][Kpad] bf16 (transposed, zero-padded)
__global__ void prep_w_k(const float* __restrict__ W, unsigned short* __restrict__ BT, int K, int Kpad) {
    int i = blockIdx.x * 256 + threadIdx.x;
    if (i < 256 * Kpad) {
        int n = i / Kpad, k = i % Kpad;
        BT[i] = (k < K) ? f2bf(W[(size_t)k * 256 + n]) : (unsigned short)0;
    }
}

// ---------------- segment mean ----------------
__global__ void molstart_k(const int* __restrict__ seg, int* __restrict__ ms) {
    int m = blockIdx.x * 256 + threadIdx.x;
    if (m <= NMOL) {
        int lo = 0, hi = NA;
        while (lo < hi) { int mid = (lo + hi) >> 1; if (seg[mid] < m) lo = mid + 1; else hi = mid; }
        ms[m] = lo;
    }
}
__global__ __launch_bounds__(64) void mean_k(const unsigned short* __restrict__ X,
    const float* __restrict__ sc, const float* __restrict__ sh,
    const int* __restrict__ ms, float* __restrict__ out)
{
    int m = blockIdx.x, lane = threadIdx.x;
    int c0 = lane * 4;
    f32x4 s4 = *(const f32x4*)(sc + c0);
    f32x4 h4 = *(const f32x4*)(sh + c0);
    int a = ms[m], b = ms[m + 1];
    f32x4 acc{0.f, 0.f, 0.f, 0.f};
    for (int r = a; r < b; ++r) {
        u16x4 u = *(const u16x4*)(X + (size_t)r * H + c0);
        #pragma unroll
        for (int e = 0; e < 4; e++) acc[e] += fmaxf(bf2f(u[e]) * s4[e] + h4[e], 0.f);
    }
    float inv = (b > a) ? 1.0f / (float)(b - a) : 0.0f;
    #pragma unroll
    for (int e = 0; e < 4; e++) acc[e] *= inv;
    *(f32x4*)(out + (size_t)m * H + c0) = acc;
}

extern "C" void kernel_launch(void* const* d_in, const int* in_sizes, int n_in,
                              void* d_out, int out_size, void* d_ws, size_t ws_size,
                              hipStream_t stream) {
    const float* f_atoms = (const float*)d_in[0];
    const float* W_in_w  = (const float*)d_in[1];
    const float* W_in_b  = (const float*)d_in[2];
    const float* w1  = (const float*)d_in[3];
    const float* b1  = (const float*)d_in[4];
    const float* g1  = (const float*)d_in[5];
    const float* be1 = (const float*)d_in[6];
    const float* w2  = (const float*)d_in[7];
    const float* b2  = (const float*)d_in[8];
    const float* g2  = (const float*)d_in[9];
    const float* be2 = (const float*)d_in[10];
    const float* epsArr = (const float*)d_in[11];
    const int* edge = (const int*)d_in[12];
    const int* seg  = (const int*)d_in[13];
    float* out = (float*)d_out;

    char* w = (char*)d_ws;
    size_t off = 0;
    auto alloc = [&](size_t bytes) {
        char* p = w + off;
        off = (off + bytes + 255) & ~(size_t)255;
        return p;
    };
    unsigned short* X   = (unsigned short*)alloc((size_t)NA * H * 2);
    unsigned short* AGG = (unsigned short*)alloc((size_t)NA * H * 2);
    unsigned short* T1  = (unsigned short*)alloc((size_t)NA * H * 2);
    unsigned short* FA  = T1;   // overlay: FA (NA*192*2 = 38.4MB) dead before T1 is first written
    unsigned short* BTin = (unsigned short*)alloc((size_t)256 * KIN * 2);
    unsigned short* BT1[3], *BT2[3];
    for (int d = 0; d < 3; ++d) {
        BT1[d] = (unsigned short*)alloc((size_t)256 * 256 * 2);
        BT2[d] = (unsigned short*)alloc((size_t)256 * 256 * 2);
    }
    float* stSum = (float*)alloc(256 * 4);
    float* stSq  = (float*)alloc(256 * 4);   // contiguous with stSum (1024B aligned)
    float* sc1 = (float*)alloc(256 * 4);
    float* sh1 = (float*)alloc(256 * 4);
    float* sc2 = (float*)alloc(256 * 4);
    float* sh2 = (float*)alloc(256 * 4);
    int* counts   = (int*)alloc((size_t)NA * 4);
    int* rowstart = (int*)alloc((size_t)NA * 4);
    int* cursor   = (int*)alloc((size_t)NA * 4);
    int* esrc     = (int*)alloc((size_t)NE * 4);
    int* bsum     = (int*)alloc(512 * 4);
    int* ms       = (int*)alloc((NMOL + 1) * 4);

    const int* esrcIn = edge;        // edge_index[0] = src
    const int* edst   = edge + NE;   // edge_index[1] = dst

    // init scratch needed each call (ws is poisoned before timing)
    zero_i32_k<<<(NA + 255) / 256, 256, 0, stream>>>(counts, NA);
    zero_f32_k<<<2, 256, 0, stream>>>(stSum, 512);   // stSum + stSq

    // weight/feature prep (bf16, transposed, padded)
    cast_fa_k<<<(int)(((long long)NA * KIN + 255) / 256), 256, 0, stream>>>(f_atoms, FA);
    prep_w_k<<<(256 * KIN + 255) / 256, 256, 0, stream>>>(W_in_w, BTin, FDIM, KIN);
    for (int d = 0; d < 3; ++d) {
        prep_w_k<<<(256 * 256 + 255) / 256, 256, 0, stream>>>(w1 + d * 65536, BT1[d], 256, 256);
        prep_w_k<<<(256 * 256 + 255) / 256, 256, 0, stream>>>(w2 + d * 65536, BT2[d], 256, 256);
    }

    // CSR by dst
    hist_k<<<(NE + 255) / 256, 256, 0, stream>>>(edst, counts);
    scan1_k<<<391, 256, 0, stream>>>(counts, rowstart, bsum);
    scan2_k<<<1, 512, 0, stream>>>(bsum, 391);
    scan3_k<<<391, 256, 0, stream>>>(rowstart, bsum, cursor);
    fill_k<<<(NE + 255) / 256, 256, 0, stream>>>(esrcIn, edst, cursor, esrc);
    molstart_k<<<(NMOL + 256) / 256, 256, 0, stream>>>(seg, ms);

    // x = relu(f_atoms @ W_in + b_in)
    gemm_k<false, true><<<dim3(2, (NA + 127) / 128), 256, 0, stream>>>(
        FA, BTin, W_in_b, nullptr, nullptr, X, NA, KIN);

    for (int d = 0; d < 3; ++d) {
        if (d == 0)
            agg_k<false><<<(NA + 3) / 4, 256, 0, stream>>>(X, nullptr, nullptr,
                rowstart, counts, esrc, epsArr, d, AGG);
        else
            agg_k<true><<<(NA + 3) / 4, 256, 0, stream>>>(X, sc2, sh2,
                rowstart, counts, esrc, epsArr, d, AGG);
        // T1 = AGG @ w1 + b1  (raw pre-BN, bf16)
        gemm_k<false, false><<<dim3(2, (NA + 127) / 128), 256, 0, stream>>>(
            AGG, BT1[d], b1 + d * 256, nullptr, nullptr, T1, NA, 256);
        stats_k<<<256, 256, 0, stream>>>(T1, stSum, stSq);
        bnfin_k<<<1, 256, 0, stream>>>(stSum, stSq, g1 + d * 256, be1 + d * 256, sc1, sh1);
        // X(=T2) = relu(BN(T1)) @ w2 + b2  (BN+ReLU folded into A staging)
        gemm_k<true, false><<<dim3(2, (NA + 127) / 128), 256, 0, stream>>>(
            T1, BT2[d], b2 + d * 256, sc1, sh1, X, NA, 256);
        stats_k<<<256, 256, 0, stream>>>(X, stSum, stSq);
        bnfin_k<<<1, 256, 0, stream>>>(stSum, stSq, g2 + d * 256, be2 + d * 256, sc2, sh2);
    }

    // per-molecule mean of relu(BN(T2))  (BN+ReLU folded in)
    mean_k<<<NMOL, 64, 0, stream>>>(X, sc2, sh2, ms, out);
}

// Round 2
// 736.031 us; speedup vs baseline: 1.7450x; 1.7450x over previous
//
#include <hip/hip_runtime.h>
#include <hip/hip_bf16.h>

#define NA 100000
#define NE 800000
#define FDIM 133
#define KIN 192          // 133 padded to 3*64
#define H 256
#define NMOL 4096

typedef __attribute__((ext_vector_type(8))) short s16x8;
typedef __attribute__((ext_vector_type(4))) float f32x4;
typedef __attribute__((ext_vector_type(4))) unsigned short u16x4;

__device__ __forceinline__ float bf2f(unsigned short h) {
    unsigned u = ((unsigned)h) << 16;
    return __builtin_bit_cast(float, u);
}
__device__ __forceinline__ unsigned short f2bf(float f) {
    unsigned u = __builtin_bit_cast(unsigned, f);
    u = u + 0x7FFFu + ((u >> 16) & 1u);
    return (unsigned short)(u >> 16);
}

// element offset (in shorts) of 16B group g (0..7) of row (0..127) in a [128][64] bf16 tile,
// XOR-swizzled so both ds_write_b128 staging and MFMA-frag ds_read_b128 are conflict-optimal
__device__ __forceinline__ int swz(int row, int g) {
    return row * 64 + ((g ^ (row & 7)) << 3);
}

// ---------------- GEMM: C[M][256] = A[M][Kpad] * BT[256][Kpad]^T (+bias) ----------------
// A_F32:    A is fp32 [M][FDIM] (row stride FDIM, zero-pad to Kpad during staging)
// AFFINE:   A' = relu(A*aSc[k]+aSh[k]) applied during staging (folds previous BN+ReLU)
// RELU_OUT: relu on output (input layer)
// STATS:    accumulate column sum/sumsq of fp32 output (pre-round) into stSum/stSq
template<bool A_F32, bool AFFINE, bool RELU_OUT, bool STATS>
__global__ __launch_bounds__(256) void gemm_k(
    const void* __restrict__ Avoid,
    const unsigned short* __restrict__ BT,
    const float* __restrict__ bias,
    const float* __restrict__ aSc, const float* __restrict__ aSh,
    unsigned short* __restrict__ C,
    float* __restrict__ stSum, float* __restrict__ stSq,
    int M, int Kpad)
{
    __shared__ short lsA[128 * 64];
    __shared__ short lsB[128 * 64];
    __shared__ float lsSc[256], lsSh[256];
    __shared__ float lsS[128], lsQ[128];

    const int t = threadIdx.x;
    const int m0 = blockIdx.y * 128;
    const int n0 = blockIdx.x * 128;

    if (STATS && t < 128) { lsS[t] = 0.f; lsQ[t] = 0.f; }
    if (AFFINE) { lsSc[t] = aSc[t]; lsSh[t] = aSh[t]; }
    if (AFFINE) __syncthreads();

    const int sr = t >> 3;          // staging row-in-pass 0..31
    const int sg = t & 7;           // staging 16B group 0..7
    const int lane = t & 63;
    const int wid = t >> 6;
    const int wm = wid >> 1, wn = wid & 1;
    const int fr = lane & 15, fg = lane >> 4;

    f32x4 acc[4][4];
    #pragma unroll
    for (int i = 0; i < 4; i++)
        #pragma unroll
        for (int j = 0; j < 4; j++)
            acc[i][j] = f32x4{0.f, 0.f, 0.f, 0.f};

    const int nK = Kpad >> 6;
    s16x8 ra[4], rb[4];

    auto loadRegs = [&](int kc) {
        const int k0 = kc * 64;
        #pragma unroll
        for (int p = 0; p < 4; ++p) {
            int r = p * 32 + sr;
            int ga = m0 + r;
            if (A_F32) {
                const float* Af = (const float*)Avoid;
                s16x8 v;
                #pragma unroll
                for (int e = 0; e < 8; ++e) {
                    int k = k0 + sg * 8 + e;
                    float f = (ga < M && k < FDIM) ? Af[(size_t)ga * FDIM + k] : 0.f;
                    v[e] = (short)f2bf(f);
                }
                ra[p] = v;
            } else {
                const unsigned short* A = (const unsigned short*)Avoid;
                s16x8 z = {0,0,0,0,0,0,0,0};
                ra[p] = (ga < M) ? *(const s16x8*)(A + (size_t)ga * Kpad + k0 + sg * 8) : z;
            }
            rb[p] = *(const s16x8*)(BT + (size_t)(n0 + p * 32 + sr) * Kpad + k0 + sg * 8);
        }
    };
    auto writeLds = [&](int kc) {
        const int k0 = kc * 64;
        #pragma unroll
        for (int p = 0; p < 4; ++p) {
            int r = p * 32 + sr;
            s16x8 va = ra[p];
            if (AFFINE) {
                #pragma unroll
                for (int e = 0; e < 8; ++e) {
                    int k = k0 + sg * 8 + e;
                    float f = bf2f((unsigned short)va[e]);
                    f = fmaxf(f * lsSc[k] + lsSh[k], 0.f);
                    va[e] = (short)f2bf(f);
                }
            }
            *(s16x8*)&lsA[swz(r, sg)] = va;
            *(s16x8*)&lsB[swz(r, sg)] = rb[p];
        }
    };

    loadRegs(0);
    for (int kc = 0; kc < nK; ++kc) {
        writeLds(kc);
        __syncthreads();
        if (kc + 1 < nK) loadRegs(kc + 1);   // issue next-chunk loads, overlap with MFMA
        #pragma unroll
        for (int ks = 0; ks < 2; ++ks) {
            s16x8 af[4], bg[4];
            #pragma unroll
            for (int mi = 0; mi < 4; ++mi)
                af[mi] = *(const s16x8*)&lsA[swz(wm * 64 + mi * 16 + fr, ks * 4 + fg)];
            #pragma unroll
            for (int ni = 0; ni < 4; ++ni)
                bg[ni] = *(const s16x8*)&lsB[swz(wn * 64 + ni * 16 + fr, ks * 4 + fg)];
            #pragma unroll
            for (int mi = 0; mi < 4; ++mi)
                #pragma unroll
                for (int ni = 0; ni < 4; ++ni)
                    acc[mi][ni] = __builtin_amdgcn_mfma_f32_16x16x32_bf16(
                        af[mi], bg[ni], acc[mi][ni], 0, 0, 0);
        }
        __syncthreads();
    }

    // epilogue: C/D layout col = lane&15, row = (lane>>4)*4 + reg
    float bc[4];
    #pragma unroll
    for (int ni = 0; ni < 4; ++ni)
        bc[ni] = bias[n0 + wn * 64 + ni * 16 + fr];
    float cs[4] = {0.f, 0.f, 0.f, 0.f}, cq[4] = {0.f, 0.f, 0.f, 0.f};
    #pragma unroll
    for (int mi = 0; mi < 4; ++mi) {
        #pragma unroll
        for (int r = 0; r < 4; ++r) {
            int row = m0 + wm * 64 + mi * 16 + fg * 4 + r;
            if (row < M) {
                #pragma unroll
                for (int ni = 0; ni < 4; ++ni) {
                    float v = acc[mi][ni][r] + bc[ni];
                    if (RELU_OUT) v = fmaxf(v, 0.f);
                    if (STATS) { cs[ni] += v; cq[ni] += v * v; }
                    C[(size_t)row * H + n0 + wn * 64 + ni * 16 + fr] = f2bf(v);
                }
            }
        }
    }
    if (STATS) {
        #pragma unroll
        for (int ni = 0; ni < 4; ++ni) {
            atomicAdd(&lsS[wn * 64 + ni * 16 + fr], cs[ni]);
            atomicAdd(&lsQ[wn * 64 + ni * 16 + fr], cq[ni]);
        }
        __syncthreads();
        if (t < 128) {
            atomicAdd(&stSum[n0 + t], lsS[t]);
            atomicAdd(&stSq[n0 + t], lsQ[t]);
        }
    }
}

__global__ void bnfin_k(float* __restrict__ sum, float* __restrict__ sumsq,
                        const float* __restrict__ g, const float* __restrict__ be,
                        float* __restrict__ scOut, float* __restrict__ shOut) {
    int c = threadIdx.x;
    float mean = sum[c] * (1.0f / NA);
    float var = sumsq[c] * (1.0f / NA) - mean * mean;
    float sc = g[c] * rsqrtf(var + 1e-5f);
    scOut[c] = sc;
    shOut[c] = be[c] - mean * sc;
    sum[c] = 0.f; sumsq[c] = 0.f;   // ready for next use
}

// ---------------- init: zero counts + stats ----------------
__global__ void zero_k(int* __restrict__ counts, float* __restrict__ st) {
    int i = blockIdx.x * 256 + threadIdx.x;
    if (i < NA) counts[i] = 0;
    if (blockIdx.x == 0 && threadIdx.x < 256) { st[threadIdx.x] = 0.f; st[threadIdx.x + 256] = 0.f; }
}

// ---------------- CSR build ----------------
__global__ void hist_k(const int* __restrict__ dst, int* __restrict__ counts) {
    int e = blockIdx.x * 256 + threadIdx.x;
    if (e < NE) atomicAdd(&counts[dst[e]], 1);
}
__global__ void scan1_k(const int* __restrict__ counts, int* __restrict__ excl, int* __restrict__ bsum) {
    __shared__ int sd[256];
    int i = blockIdx.x * 256 + threadIdx.x;
    int c = (i < NA) ? counts[i] : 0;
    sd[threadIdx.x] = c;
    __syncthreads();
    for (int off = 1; off < 256; off <<= 1) {
        int v = (threadIdx.x >= off) ? sd[threadIdx.x - off] : 0;
        __syncthreads();
        sd[threadIdx.x] += v;
        __syncthreads();
    }
    if (i < NA) excl[i] = sd[threadIdx.x] - c;
    if (threadIdx.x == 255) bsum[blockIdx.x] = sd[255];
}
__global__ void scan2_k(int* __restrict__ bsum, int nb) {
    __shared__ int sd[512];
    int t = threadIdx.x;
    int v = (t < nb) ? bsum[t] : 0;
    sd[t] = v;
    __syncthreads();
    for (int off = 1; off < 512; off <<= 1) {
        int u = (t >= off) ? sd[t - off] : 0;
        __syncthreads();
        sd[t] += u;
        __syncthreads();
    }
    if (t < nb) bsum[t] = sd[t] - v;
}
__global__ void scan3_k(int* __restrict__ rowstart, const int* __restrict__ bsum, int* __restrict__ cursor) {
    int i = blockIdx.x * 256 + threadIdx.x;
    if (i < NA) {
        int v = rowstart[i] + bsum[blockIdx.x];
        rowstart[i] = v;
        cursor[i] = v;
    }
}
__global__ void fill_k(const int* __restrict__ src, const int* __restrict__ dstArr,
                       int* __restrict__ cursor, int* __restrict__ esrc) {
    int e = blockIdx.x * 256 + threadIdx.x;
    if (e < NE) {
        int d = dstArr[e];
        int pos = atomicAdd(&cursor[d], 1);
        esrc[pos] = src[e];
    }
}

// ---------------- neighbor aggregation: AGG[r] = (1+eps)*x'[r] + sum_{s in N(r)} x'[s] ----------------
// AFF: x' = relu(X*sc+sh) (folds previous layer's BN+ReLU); else x' = X
// one row per wave; lanes 0-31 / 32-63 walk alternate neighbors (2 chains), 16B/lane loads,
// manual 2x unroll -> 4 gather loads in flight per wave; __shfl_xor(32) merge at the end
template<bool AFF>
__global__ __launch_bounds__(256) void agg_k(const unsigned short* __restrict__ X,
    const float* __restrict__ sc, const float* __restrict__ sh,
    const int* __restrict__ rowstart, const int* __restrict__ counts,
    const int* __restrict__ esrc, const float* __restrict__ epsArr, int layer,
    unsigned short* __restrict__ AGG)
{
    int wid = threadIdx.x >> 6, lane = threadIdx.x & 63;
    int row = blockIdx.x * 4 + wid;
    if (row >= NA) return;
    int half = lane >> 5;
    int c0 = (lane & 31) * 8;

    float s8[8], h8[8];
    if (AFF) {
        f32x4 a = *(const f32x4*)(sc + c0), b = *(const f32x4*)(sc + c0 + 4);
        f32x4 c = *(const f32x4*)(sh + c0), d = *(const f32x4*)(sh + c0 + 4);
        #pragma unroll
        for (int e = 0; e < 4; e++) { s8[e] = a[e]; s8[e + 4] = b[e]; h8[e] = c[e]; h8[e + 4] = d[e]; }
    }

    float a0[8] = {0,0,0,0,0,0,0,0}, a1[8] = {0,0,0,0,0,0,0,0};
    auto gath = [&](int i, float* a) {
        int sr2 = esrc[i];
        s16x8 u = *(const s16x8*)(X + (size_t)sr2 * H + c0);
        #pragma unroll
        for (int e = 0; e < 8; e++) {
            float f = bf2f((unsigned short)u[e]);
            if (AFF) f = fmaxf(f * s8[e] + h8[e], 0.f);
            a[e] += f;
        }
    };

    int s = rowstart[row], eEnd = s + counts[row];
    int i = s + half;
    for (; i + 2 < eEnd; i += 4) { gath(i, a0); gath(i + 2, a1); }
    if (i < eEnd) gath(i, a0);

    if (half == 0) {   // self term, added once
        float e1 = 1.0f + epsArr[layer];
        s16x8 u = *(const s16x8*)(X + (size_t)row * H + c0);
        #pragma unroll
        for (int e = 0; e < 8; e++) {
            float f = bf2f((unsigned short)u[e]);
            if (AFF) f = fmaxf(f * s8[e] + h8[e], 0.f);
            a0[e] += f * e1;
        }
    }

    s16x8 o;
    #pragma unroll
    for (int e = 0; e < 8; e++) {
        float tot = a0[e] + a1[e];
        tot += __shfl_xor(tot, 32);
        o[e] = (short)f2bf(tot);
    }
    if (half == 0)
        *(s16x8*)(AGG + (size_t)row * H + c0) = o;
}

// ---------------- weight prep: all 7 matrices -> bf16 transposed [256][Kpad], one kernel ----------------
// layout: BTin (256*192) | d0w1 | d0w2 | d1w1 | d1w2 | d2w1 | d2w2 (each 256*256)
__global__ void prep_all_k(const float* __restrict__ Win, const float* __restrict__ w1,
                           const float* __restrict__ w2, unsigned short* __restrict__ BTall) {
    int i = blockIdx.x * 256 + threadIdx.x;
    const int NIN = 256 * KIN;
    if (i < NIN) {
        int n = i / KIN, k = i % KIN;
        BTall[i] = (k < FDIM) ? f2bf(Win[(size_t)k * 256 + n]) : (unsigned short)0;
    } else if (i < NIN + 6 * 65536) {
        int j = i - NIN;
        int d = j >> 16, r = j & 65535;
        int n = r >> 8, k = r & 255;
        const float* W = (d & 1) ? w2 : w1;
        BTall[i] = f2bf(W[(size_t)(d >> 1) * 65536 + (size_t)k * 256 + n]);
    }
}

// ---------------- segment mean ----------------
__global__ void molstart_k(const int* __restrict__ seg, int* __restrict__ ms) {
    int m = blockIdx.x * 256 + threadIdx.x;
    if (m <= NMOL) {
        int lo = 0, hi = NA;
        while (lo < hi) { int mid = (lo + hi) >> 1; if (seg[mid] < m) lo = mid + 1; else hi = mid; }
        ms[m] = lo;
    }
}
__global__ __launch_bounds__(64) void mean_k(const unsigned short* __restrict__ X,
    const float* __restrict__ sc, const float* __restrict__ sh,
    const int* __restrict__ ms, float* __restrict__ out)
{
    int m = blockIdx.x, lane = threadIdx.x;
    int c0 = lane * 4;
    f32x4 s4 = *(const f32x4*)(sc + c0);
    f32x4 h4 = *(const f32x4*)(sh + c0);
    int a = ms[m], b = ms[m + 1];
    f32x4 acc{0.f, 0.f, 0.f, 0.f};
    for (int r = a; r < b; ++r) {
        u16x4 u = *(const u16x4*)(X + (size_t)r * H + c0);
        #pragma unroll
        for (int e = 0; e < 4; e++) acc[e] += fmaxf(bf2f(u[e]) * s4[e] + h4[e], 0.f);
    }
    float inv = (b > a) ? 1.0f / (float)(b - a) : 0.0f;
    #pragma unroll
    for (int e = 0; e < 4; e++) acc[e] *= inv;
    *(f32x4*)(out + (size_t)m * H + c0) = acc;
}

extern "C" void kernel_launch(void* const* d_in, const int* in_sizes, int n_in,
                              void* d_out, int out_size, void* d_ws, size_t ws_size,
                              hipStream_t stream) {
    const float* f_atoms = (const float*)d_in[0];
    const float* W_in_w  = (const float*)d_in[1];
    const float* W_in_b  = (const float*)d_in[2];
    const float* w1  = (const float*)d_in[3];
    const float* b1  = (const float*)d_in[4];
    const float* g1  = (const float*)d_in[5];
    const float* be1 = (const float*)d_in[6];
    const float* w2  = (const float*)d_in[7];
    const float* b2  = (const float*)d_in[8];
    const float* g2  = (const float*)d_in[9];
    const float* be2 = (const float*)d_in[10];
    const float* epsArr = (const float*)d_in[11];
    const int* edge = (const int*)d_in[12];
    const int* seg  = (const int*)d_in[13];
    float* out = (float*)d_out;

    char* w = (char*)d_ws;
    size_t off = 0;
    auto alloc = [&](size_t bytes) {
        char* p = w + off;
        off = (off + bytes + 255) & ~(size_t)255;
        return p;
    };
    unsigned short* X   = (unsigned short*)alloc((size_t)NA * H * 2);
    unsigned short* AGG = (unsigned short*)alloc((size_t)NA * H * 2);
    unsigned short* T1  = (unsigned short*)alloc((size_t)NA * H * 2);
    unsigned short* BTall = (unsigned short*)alloc(((size_t)256 * KIN + 6 * 65536) * 2);
    float* stSum = (float*)alloc(256 * 4);
    float* stSq  = (float*)alloc(256 * 4);   // contiguous with stSum
    float* sc1 = (float*)alloc(256 * 4);
    float* sh1 = (float*)alloc(256 * 4);
    float* sc2 = (float*)alloc(256 * 4);
    float* sh2 = (float*)alloc(256 * 4);
    int* counts   = (int*)alloc((size_t)NA * 4);
    int* rowstart = (int*)alloc((size_t)NA * 4);
    int* cursor   = (int*)alloc((size_t)NA * 4);
    int* esrc     = (int*)alloc((size_t)NE * 4);
    int* bsum     = (int*)alloc(512 * 4);
    int* ms       = (int*)alloc((NMOL + 1) * 4);

    unsigned short* BTin = BTall;
    unsigned short* BT1[3], *BT2[3];
    for (int d = 0; d < 3; ++d) {
        BT1[d] = BTall + 256 * KIN + (size_t)(2 * d) * 65536;
        BT2[d] = BTall + 256 * KIN + (size_t)(2 * d + 1) * 65536;
    }

    const int* esrcIn = edge;        // edge_index[0] = src
    const int* edst   = edge + NE;   // edge_index[1] = dst

    zero_k<<<(NA + 255) / 256, 256, 0, stream>>>(counts, stSum);
    prep_all_k<<<(256 * KIN + 6 * 65536 + 255) / 256, 256, 0, stream>>>(W_in_w, w1, w2, BTall);

    // CSR by dst
    hist_k<<<(NE + 255) / 256, 256, 0, stream>>>(edst, counts);
    scan1_k<<<391, 256, 0, stream>>>(counts, rowstart, bsum);
    scan2_k<<<1, 512, 0, stream>>>(bsum, 391);
    scan3_k<<<391, 256, 0, stream>>>(rowstart, bsum, cursor);
    fill_k<<<(NE + 255) / 256, 256, 0, stream>>>(esrcIn, edst, cursor, esrc);
    molstart_k<<<(NMOL + 256) / 256, 256, 0, stream>>>(seg, ms);

    // x = relu(f_atoms @ W_in + b_in)   (f32 A staged directly)
    gemm_k<true, false, true, false><<<dim3(2, (NA + 127) / 128), 256, 0, stream>>>(
        f_atoms, BTin, W_in_b, nullptr, nullptr, X, nullptr, nullptr, NA, KIN);

    for (int d = 0; d < 3; ++d) {
        if (d == 0)
            agg_k<false><<<(NA + 3) / 4, 256, 0, stream>>>(X, nullptr, nullptr,
                rowstart, counts, esrc, epsArr, d, AGG);
        else
            agg_k<true><<<(NA + 3) / 4, 256, 0, stream>>>(X, sc2, sh2,
                rowstart, counts, esrc, epsArr, d, AGG);
        // T1 = AGG @ w1 + b1  (raw pre-BN, bf16) + fused column stats
        gemm_k<false, false, false, true><<<dim3(2, (NA + 127) / 128), 256, 0, stream>>>(
            AGG, BT1[d], b1 + d * 256, nullptr, nullptr, T1, stSum, stSq, NA, 256);
        bnfin_k<<<1, 256, 0, stream>>>(stSum, stSq, g1 + d * 256, be1 + d * 256, sc1, sh1);
        // X = relu(BN(T1)) @ w2 + b2  (BN+ReLU folded into A staging) + fused stats
        gemm_k<false, true, false, true><<<dim3(2, (NA + 127) / 128), 256, 0, stream>>>(
            T1, BT2[d], b2 + d * 256, sc1, sh1, X, stSum, stSq, NA, 256);
        bnfin_k<<<1, 256, 0, stream>>>(stSum, stSq, g2 + d * 256, be2 + d * 256, sc2, sh2);
    }

    // per-molecule mean of relu(BN(X))  (BN+ReLU folded in)
    mean_k<<<NMOL, 64, 0, stream>>>(X, sc2, sh2, ms, out);
}